// Round 4
// baseline (360.466 us; speedup 1.0000x reference)
//
#include <hip/hip_runtime.h>
#include <hip/hip_bf16.h>

// B=4, NV=50000, NRINGS=3, NDIRS=16, NF=16. All f32 except expmap(int32).
// MFMA: per vertex D[16d x 16f] = A[16d x 144k] * W[144k x 16f], k = dd*9 + q.
// R10 = R6 (known-good, 347us) + LDS-transpose epilogue ONLY.
//   - mfma(Y, W) order kept EXACTLY as R6 (operand-swap path closed: R9 proved
//     the A-operand lane map is not pinned by R6's pass, because A is a
//     structured circulant; generic W as A-operand misplaces -> wrong output).
//   - Old epilogue: 16 scattered global_store_dword per lane (~83us of issue).
//     New: lane writes relu(acc+bias) to LDS f-major (fv[f*16+d]) as one
//     ds_write_b128 per vertex (acc regs are d-consecutive; bank groups
//     uniform 8 lanes/group = BW-limited, stall-free). After __syncthreads,
//     thread (v=t>>4, d=t&15) reads 16x ds_read_b32 (banks uniform 2-way =
//     free) and emits 4x global_store_dwordx4. Store insts per lane: 16 -> 4.
//   - yls is reused for the f32 transpose (1024B needed <= 1216B per-vertex
//     region); two __syncthreads fence the reuse (conservative).
#define NBATCH 4
#define NV     50000
#define VPB    16          // vertices per block (4 waves x 4 vertices)
#define VST    304         // per-copy stride in bf16 elems (even, >=296)

typedef __attribute__((ext_vector_type(8))) short short8;
typedef __attribute__((ext_vector_type(4))) float floatx4;

// ---- pre-kernel: build per-lane W fragments (bf16) into d_ws ----
// layout: lane*40 + kc*8 ushorts (16B per chunk, 80B per lane, 5120B total)
__global__ void build_wfrag(const float* __restrict__ kw,
                            unsigned short* __restrict__ wbuf) {
    const int lane = threadIdx.x;      // 0..63
    const int fcol = lane & 15;
    const int quad = lane >> 4;
    #pragma unroll
    for (int kc = 0; kc < 5; ++kc) {
        unsigned short v[8];
        #pragma unroll
        for (int j = 0; j < 8; ++j) {
            int k = kc * 32 + quad * 8 + j;
            unsigned short b = 0;
            if (k < 144) {
                int dd = k / 9;
                int q  = k - dd * 9;
                int r  = q / 3;
                int c  = q - r * 3;
                __hip_bfloat16 h = __float2bfloat16(kw[((r * 16 + dd) * 3 + c) * 16 + fcol]);
                __builtin_memcpy(&b, &h, 2);
            }
            v[j] = b;
        }
        __builtin_memcpy(wbuf + lane * 40 + kc * 8, v, 16);
    }
}

__global__ __launch_bounds__(256, 4)
void input3d_mfma(const float* __restrict__ bp,     // (B,NV,3)
                  const float* __restrict__ fr,     // (B,NV,3,3)
                  const int2*  __restrict__ em,     // (B,NV,3,16) int pairs
                  const unsigned short* __restrict__ wbuf, // prebuilt W frags
                  const float* __restrict__ bias,   // (16)
                  float*       __restrict__ out)    // (B,NV,16,16)
{
    __shared__ __align__(16) unsigned short yls[VPB * 2 * VST];   // 19456 B

    const int tid  = threadIdx.x;
    const int bv0  = blockIdx.x * VPB;
    const int lane = tid & 63;
    const int wid  = tid >> 6;
    const int fcol = lane & 15;
    const int quad = lane >> 4;

    // ---- load prebuilt W fragments: 5 x dwordx4 ----
    union WU { unsigned short s[8]; short8 v; };
    WU wf[5];
    const unsigned short* wl = wbuf + lane * 40;
    #pragma unroll
    for (int kc = 0; kc < 5; ++kc)
        __builtin_memcpy(&wf[kc].s[0], wl + kc * 8, 16);
    const float bsf = bias[fcol];

    // ---- staging: thread = (v = tid>>4, dir = tid&15) ----
    {
        const int v   = tid >> 4;
        const int dir = tid & 15;
        const int bv  = bv0 + v;
        float F[9];
        __builtin_memcpy(&F[0], fr + (size_t)bv * 9, 16);
        __builtin_memcpy(&F[4], fr + (size_t)bv * 9 + 4, 16);
        F[8] = fr[(size_t)bv * 9 + 8];
        const float c0 = bp[bv * 3 + 0];
        const float c1 = bp[bv * 3 + 1];
        const float c2 = bp[bv * 3 + 2];

        unsigned short val[9];
        #pragma unroll
        for (int r = 0; r < 3; ++r) {
            int2 e  = em[bv * 48 + r * 16 + dir];
            int nb  = e.x * NV + e.y;
            float dx = bp[nb * 3 + 0] - c0;
            float dy = bp[nb * 3 + 1] - c1;
            float dz = bp[nb * 3 + 2] - c2;
            #pragma unroll
            for (int c = 0; c < 3; ++c) {
                float yv = F[c * 3 + 0] * dx + F[c * 3 + 1] * dy + F[c * 3 + 2] * dz;
                __hip_bfloat16 h = __float2bfloat16(yv);
                unsigned short us;
                __builtin_memcpy(&us, &h, 2);
                val[r * 3 + c] = us;
            }
        }

        // packed 9-element group writes (4 x b32 + 1 x u16 per group)
        unsigned short* buf = &yls[v * 2 * VST];
        unsigned int pe[4], po[4];
        #pragma unroll
        for (int i = 0; i < 4; ++i) {
            pe[i] = (unsigned int)val[2 * i]     | ((unsigned int)val[2 * i + 1] << 16);
            po[i] = (unsigned int)val[2 * i + 1] | ((unsigned int)val[2 * i + 2] << 16);
        }
        const int n0 = dir * 9;
        // even-start group: dwords at s, tail u16 at s+8
        auto storeE = [&](int s) {
            unsigned int* p = (unsigned int*)(buf + s);
            p[0] = pe[0]; p[1] = pe[1]; p[2] = pe[2]; p[3] = pe[3];
            buf[s + 8] = val[8];
        };
        // odd-start group: head u16 at s, dwords at s+1
        auto storeO = [&](int s) {
            buf[s] = val[0];
            unsigned int* p = (unsigned int*)(buf + s + 1);
            p[0] = po[0]; p[1] = po[1]; p[2] = po[2]; p[3] = po[3];
        };
        if (dir & 1) {                 // n0 odd
            storeO(n0);
            storeE(VST + n0 - 1);
            if (dir < 15) { storeO(n0 + 144); storeE(VST + n0 + 143); }
        } else {                       // n0 even
            storeE(n0);
            storeO(VST + n0 - 1);
            if (dir < 15) { storeE(n0 + 144); storeO(VST + n0 + 143); }
        }
    }
    __syncthreads();

    // ---- per wave: 4 vertices, 5 MFMA each (K=144 exact) ----
    floatx4 acc[4] = {{0.f,0.f,0.f,0.f},{0.f,0.f,0.f,0.f},
                      {0.f,0.f,0.f,0.f},{0.f,0.f,0.f,0.f}};
    const unsigned short* abase[4];
    #pragma unroll
    for (int i = 0; i < 4; ++i) {
        int v = wid * 4 + i;
        abase[i] = &yls[v * 2 * VST + ((fcol & 1) ? (VST - 1) : 0) + 9 * fcol];
    }
    #pragma unroll
    for (int kc = 0; kc < 4; ++kc) {
        const int s = kc * 32 + quad * 8;
        #pragma unroll
        for (int i = 0; i < 4; ++i) {
            const unsigned int* pa = (const unsigned int*)(abase[i] + s);
            union { unsigned int u[4]; short8 s8; } a;
            a.u[0] = pa[0]; a.u[1] = pa[1]; a.u[2] = pa[2]; a.u[3] = pa[3];
            acc[i] = __builtin_amdgcn_mfma_f32_16x16x32_bf16(a.s8, wf[kc].v, acc[i], 0, 0, 0);
        }
    }
    {   // chunk 4: k = 128 + quad*8 + j; valid k<144 only for quads 0,1.
        const int s = 128 + quad * 8;
        #pragma unroll
        for (int i = 0; i < 4; ++i) {
            union { unsigned int u[4]; short8 s8; } a;
            if (quad < 2) {
                const unsigned int* pa = (const unsigned int*)(abase[i] + s);
                a.u[0] = pa[0]; a.u[1] = pa[1]; a.u[2] = pa[2]; a.u[3] = pa[3];
            } else {
                a.u[0] = 0; a.u[1] = 0; a.u[2] = 0; a.u[3] = 0;
            }
            acc[i] = __builtin_amdgcn_mfma_f32_16x16x32_bf16(a.s8, wf[4].v, acc[i], 0, 0, 0);
        }
    }

    // ---- epilogue step 1: bias+relu, write f-major transpose to LDS ----
    // acc[i][rr] = D[d=quad*4+rr][f=fcol] (R6-proven). fv[f*16 + d], d-run is
    // rr-contiguous -> one ds_write_b128 per vertex. 16B-group =
    // (quad + 4*((i+fcol)&1)) mod 8 -> 8 lanes/group uniform -> stall-free.
    __syncthreads();   // all waves done reading bf16 fragments from yls
    #pragma unroll
    for (int i = 0; i < 4; ++i) {
        const int vloc = wid * 4 + i;
        float* fv = reinterpret_cast<float*>(&yls[vloc * 2 * VST]);
        floatx4 o;
        #pragma unroll
        for (int rr = 0; rr < 4; ++rr) {
            float t = acc[i][rr] + bsf;
            o[rr] = t > 0.f ? t : 0.f;
        }
        *reinterpret_cast<floatx4*>(fv + fcol * 16 + quad * 4) = o;
    }
    __syncthreads();

    // ---- epilogue step 2: read back per-(v,d), store coalesced float4 ----
    // thread t: vloc=t>>4 (its own wave's vertices), dloc=t&15.
    // bank = dloc + 16*((vloc+cc)&1) -> uniform 2-way (free).
    {
        const int vloc = tid >> 4;
        const int dloc = tid & 15;
        const float* fv = reinterpret_cast<const float*>(&yls[vloc * 2 * VST]);
        float* ob = out + (size_t)(bv0 + vloc) * 256 + dloc * 16;
        #pragma unroll
        for (int c = 0; c < 4; ++c) {
            floatx4 o;
            #pragma unroll
            for (int cc = 0; cc < 4; ++cc)
                o[cc] = fv[(4 * c + cc) * 16 + dloc];
            *reinterpret_cast<floatx4*>(ob + 4 * c) = o;
        }
    }
}

extern "C" void kernel_launch(void* const* d_in, const int* in_sizes, int n_in,
                              void* d_out, int out_size, void* d_ws, size_t ws_size,
                              hipStream_t stream) {
    const float* bp   = (const float*)d_in[0];
    const float* fr   = (const float*)d_in[1];
    const int2*  em   = (const int2*)d_in[2];
    const float* kw   = (const float*)d_in[3];
    const float* bias = (const float*)d_in[4];
    float* out = (float*)d_out;
    unsigned short* wbuf = (unsigned short*)d_ws;   // 5120 B used

    build_wfrag<<<1, 64, 0, stream>>>(kw, wbuf);

    const int total_bv = NBATCH * NV;          // 200000
    const int grid = total_bv / VPB;           // 12500 blocks
    input3d_mfma<<<grid, 256, 0, stream>>>(bp, fr, em, wbuf, bias, out);
}